// Round 16
// baseline (304.164 us; speedup 1.0000x reference)
//
#include <hip/hip_runtime.h>
#include <hip/hip_bf16.h>
#include <stdint.h>

// GatedScreeningTile: B=2 N=2048 DIM=2048 H=16 DK=64 DV=128 DIM_INNER=3072
// R16: gemmP2 mid-tile barrier removed (provably correctness-unneeded): single
// barrier per K-tile; mh1's ds_reads + late stages issued between the two MFMA
// clusters so LDS latency hides under mh0's MFMAs (m233 2-phase-lockstep fix).
// Everything else identical to R15 (fused q-norm/gate attn, 3-slot pipelines).

typedef unsigned short u16;
typedef __bf16 bf16x8 __attribute__((ext_vector_type(8)));
typedef u16 u16x8 __attribute__((ext_vector_type(8)));
typedef float f32x4 __attribute__((ext_vector_type(4)));
typedef float f32x16 __attribute__((ext_vector_type(16)));
typedef int i32x4 __attribute__((ext_vector_type(4)));

#define DEVINL __device__ __forceinline__

DEVINL u16 f2bf(float f) {
  union { float f; uint32_t u; } v; v.f = f;
  uint32_t r = (v.u + 0x7FFFu + ((v.u >> 16) & 1u)) >> 16;
  return (u16)r;
}
DEVINL float bf2f(u16 x) {
  union { uint32_t u; float f; } v; v.u = ((uint32_t)x) << 16;
  return v.f;
}
DEVINL bf16x8 as_bf(u16x8 v) { return __builtin_bit_cast(bf16x8, v); }

typedef const __attribute__((address_space(1))) uint32_t* gptr_t;
typedef __attribute__((address_space(3))) uint32_t* lptr_t;
DEVINL void gload_lds16(const void* g, void* l) {
  __builtin_amdgcn_global_load_lds((gptr_t)g, (lptr_t)l, 16, 0, 0);
}

DEVINL f32x4 mfma16(u16x8 a, u16x8 b, f32x4 c) {
  return __builtin_amdgcn_mfma_f32_16x16x32_bf16(as_bf(a), as_bf(b), c, 0, 0, 0);
}
DEVINL f32x16 mfma32(u16x8 a, u16x8 b, f32x16 c) {
  return __builtin_amdgcn_mfma_f32_32x32x16_bf16(as_bf(a), as_bf(b), c, 0, 0, 0);
}

// ---------------- fp32 -> bf16 convert (same layout) ----------------
__global__ void k_cvt(const float* __restrict__ src, u16* __restrict__ dst, int n) {
  int i = (blockIdx.x * blockDim.x + threadIdx.x) * 4;
  int stride = gridDim.x * blockDim.x * 4;
  for (; i < n; i += stride) {
    float4 f = *(const float4*)(src + i);
    ushort4 o;
    o.x = f2bf(f.x); o.y = f2bf(f.y); o.z = f2bf(f.z); o.w = f2bf(f.w);
    *(ushort4*)(dst + i) = o;
  }
}

// ---------------- fp32 (RxC) -> bf16 transposed (CxR) ----------------
__global__ void k_cvtT(const float* __restrict__ src, u16* __restrict__ dst, int R, int C) {
  __shared__ float tile[32][33];
  int c0 = blockIdx.x * 32, r0 = blockIdx.y * 32;
  int tc = threadIdx.x & 31, tr = threadIdx.x >> 5;  // tr 0..7
#pragma unroll
  for (int i = 0; i < 4; i++) {
    int r = tr + i * 8;
    tile[r][tc] = src[(size_t)(r0 + r) * C + c0 + tc];
  }
  __syncthreads();
#pragma unroll
  for (int i = 0; i < 4; i++) {
    int r = tr + i * 8;  // row in dst tile (= src col)
    dst[(size_t)(c0 + r) * R + r0 + tc] = f2bf(tile[tc][r]);
  }
}

// ---------------- k_gemmP2: merged projection, 256x384, BK=32, triple-buffer ----------------
// R12 outer pipeline (3 slots, stage 2 tiles ahead, tile-top counted vmcnt(5));
// R16: ONE barrier per tile; mh1 reads + late stages between the MFMA clusters.
__global__ __launch_bounds__(512, 1) void k_gemmP2(const u16* __restrict__ A,
                                                   const u16* __restrict__ Bt,
                                                   u16* __restrict__ C,
                                                   int Nt, int K) {
  extern __shared__ char smem[];
  u16* As = (u16*)smem;             // [3][256][32] u16, slot stride 8192
  u16* Bs = (u16*)(smem + 49152);   // [3][384][32] u16, slot stride 12288

  const int tid = threadIdx.x, lane = tid & 63, wid = tid >> 6;

  const int bid = blockIdx.x;
  const int xcd = bid & 7, idx = bid >> 3;  // idx 0..31
  const int m0 = (idx & 15) * 256;
  const int n0 = (xcd * 2 + (idx >> 4)) * 384;

  const int wm = (wid >> 2) * 128, wn = (wid & 3) * 96;
  const int fr = lane & 15, hi = lane >> 4, frow = hi * 4;
  const int kg = (fr >> 1) & 3;
  const int gofs = (hi ^ kg) << 3;

  f32x4 acc[2][4][6] = {};

  const int sg = ((lane & 3) ^ ((lane >> 3) & 3)) << 3;
  const int srow = wid * 16 + (lane >> 2);
  const u16* gA0 = A + (size_t)(m0 + srow) * K + sg;
  const u16* gB0 = Bt + (size_t)(n0 + srow) * K + sg;
  const size_t r128 = (size_t)128 * K;
  const int dwave = wid * 512;

#define SA(S, I, KT) gload_lds16(gA0 + (size_t)(I) * r128 + (KT), As + (S) * 8192 + (I) * 4096 + dwave)
#define SB(S, I, KT) gload_lds16(gB0 + (size_t)(I) * r128 + (KT), Bs + (S) * 12288 + (I) * 4096 + dwave)

  SA(0, 0, 0); SA(0, 1, 0); SB(0, 0, 0); SB(0, 1, 0); SB(0, 2, 0);
  SA(1, 0, 32); SA(1, 1, 32); SB(1, 0, 32); SB(1, 1, 32); SB(1, 2, 32);

  const int NTI = K >> 5;  // 64
  int s = 0;
  for (int t = 0; t < NTI; t++) {
    const int s2 = (s + 2 >= 3) ? s - 1 : s + 2;
    const int ktn = (t + 2) << 5;
    const bool do_stage = (t + 2) < NTI;

    // tile top: stage(t) landed (issued 2 tiles ago); stage(t+1) keeps flying
    if (t < NTI - 1) {
      asm volatile("s_waitcnt vmcnt(5)" ::: "memory");
    } else {
      asm volatile("s_waitcnt vmcnt(0)" ::: "memory");
    }
    __builtin_amdgcn_s_barrier();
    asm volatile("" ::: "memory");

    const u16* Ab = As + s * 8192;
    const u16* Bb = Bs + s * 12288;

    // reads for mh0 + all B frags; early stages
    u16x8 bf[6], af0[4], af1[4];
#pragma unroll
    for (int nj = 0; nj < 6; nj++)
      bf[nj] = *(const u16x8*)(Bb + (wn + nj * 16 + fr) * 32 + gofs);
#pragma unroll
    for (int mi = 0; mi < 4; mi++)
      af0[mi] = *(const u16x8*)(Ab + (wm + mi * 16 + fr) * 32 + gofs);
    if (do_stage) { SA(s2, 0, ktn); SA(s2, 1, ktn); SB(s2, 0, ktn); }

    // mh1 reads issued BEFORE mh0's MFMA cluster: LDS latency hides under MFMA
#pragma unroll
    for (int mi = 0; mi < 4; mi++)
      af1[mi] = *(const u16x8*)(Ab + (wm + 64 + mi * 16 + fr) * 32 + gofs);
    if (do_stage) { SB(s2, 1, ktn); SB(s2, 2, ktn); }

    __builtin_amdgcn_s_setprio(1);
#pragma unroll
    for (int mi = 0; mi < 4; mi++)
#pragma unroll
      for (int nj = 0; nj < 6; nj++)
        acc[0][mi][nj] = mfma16(af0[mi], bf[nj], acc[0][mi][nj]);
#pragma unroll
    for (int mi = 0; mi < 4; mi++)
#pragma unroll
      for (int nj = 0; nj < 6; nj++)
        acc[1][mi][nj] = mfma16(af1[mi], bf[nj], acc[1][mi][nj]);
    __builtin_amdgcn_s_setprio(0);

    s = (s + 1 >= 3) ? 0 : s + 1;
  }
#undef SA
#undef SB

#pragma unroll
  for (int mh = 0; mh < 2; mh++)
#pragma unroll
    for (int mi = 0; mi < 4; mi++)
#pragma unroll
      for (int nj = 0; nj < 6; nj++)
#pragma unroll
        for (int j = 0; j < 4; j++) {
          const size_t row = m0 + wm + mh * 64 + mi * 16 + frow + j;
          const size_t col = n0 + wn + nj * 16 + fr;
          C[row * Nt + col] = f2bf(acc[mh][mi][nj][j]);
        }
}

// ---------------- k_gemmU: final projection (grid 256, TRIPLE-buffer, counted vmcnt) ----------------
template <int NI, int F32OUT>
__global__ __launch_bounds__(512, 1) void k_gemmU(const u16* __restrict__ A,
                                                  const u16* __restrict__ Bt,
                                                  void* __restrict__ Cout,
                                                  int Nt, int K) {
  constexpr int BN = NI * 128;
  constexpr int NLB = BN / 64;
  constexpr int ABUF = 128 * 64;
  constexpr int BBUF = BN * 64;
  extern __shared__ char smem[];
  u16* As = (u16*)smem;                   // [3][128][64]
  u16* Bs = (u16*)(smem + 3 * ABUF * 2);  // [3][BN][64]

  const int tid = threadIdx.x, lane = tid & 63, wid = tid >> 6;

  const int NPN = Nt / BN;
  const int bid = blockIdx.x;
  const int xcd = bid & 7, idx = bid >> 3;
  const int npx = NPN >> 3;
  const int m0 = (idx & 31) * 128;
  const int n0 = (xcd * npx + (idx >> 5)) * BN;

  const int mq = (wid >> 2) * 32, nq = (wid & 3) * (BN / 8);
  const int fr = lane & 15, hi = lane >> 4, frow = hi * 4, rb7 = fr & 7;

  f32x4 acc[2][2][2][NI] = {};

  const int schunk = ((lane & 7) ^ ((lane >> 3) & 7)) << 3;
  const int srow = wid * 8 + (lane >> 3);
  const u16* ga0 = A + (size_t)(m0 + srow) * K + schunk;
  const u16* gb0 = Bt + (size_t)(n0 + srow) * K + schunk;
  const size_t l64 = (size_t)64 * K;
  const int dwave = wid * 512;

#define STG(T, S)                                                                     \
  {                                                                                   \
    const int kt_ = (T) << 6;                                                         \
    _Pragma("unroll") for (int i = 0; i < 2; i++)                                     \
        gload_lds16(ga0 + (size_t)i * l64 + kt_, As + (S) * ABUF + i * 4096 + dwave); \
    _Pragma("unroll") for (int i = 0; i < NLB; i++)                                   \
        gload_lds16(gb0 + (size_t)i * l64 + kt_, Bs + (S) * BBUF + i * 4096 + dwave); \
  }

  STG(0, 0);
  STG(1, 1);

  const int NTI = K >> 6;
  int s = 0;
  for (int t = 0; t < NTI; t++) {
    if (t < NTI - 1) {
      if constexpr (NI == 2) asm volatile("s_waitcnt vmcnt(6) lgkmcnt(0)" ::: "memory");
      else asm volatile("s_waitcnt vmcnt(8) lgkmcnt(0)" ::: "memory");
    } else {
      asm volatile("s_waitcnt vmcnt(0) lgkmcnt(0)" ::: "memory");
    }
    __builtin_amdgcn_s_barrier();
    asm volatile("" ::: "memory");

    if (t + 2 < NTI) {
      const int s2 = (s + 2 >= 3) ? s - 1 : s + 2;
      STG(t + 2, s2);
    }

    const u16* Ab = As + s * ABUF;
    const u16* Bb = Bs + s * BBUF;

    u16x8 af[2][2][2], bf[2][NI][2];
#pragma unroll
    for (int MH = 0; MH < 2; MH++)
#pragma unroll
      for (int mi = 0; mi < 2; mi++)
#pragma unroll
        for (int kk = 0; kk < 2; kk++) {
          const int row = MH * 64 + mq + mi * 16 + fr;
          af[MH][mi][kk] = *(const u16x8*)(Ab + row * 64 + (((kk * 4 + hi) ^ rb7) << 3));
        }
#pragma unroll
    for (int NH = 0; NH < 2; NH++)
#pragma unroll
      for (int ni = 0; ni < NI; ni++)
#pragma unroll
        for (int kk = 0; kk < 2; kk++) {
          const int row = NH * (BN / 2) + nq + ni * 16 + fr;
          bf[NH][ni][kk] = *(const u16x8*)(Bb + row * 64 + (((kk * 4 + hi) ^ rb7) << 3));
        }

    __builtin_amdgcn_s_setprio(1);
#pragma unroll
    for (int kk = 0; kk < 2; kk++)
#pragma unroll
      for (int MH = 0; MH < 2; MH++)
#pragma unroll
        for (int mi = 0; mi < 2; mi++)
#pragma unroll
          for (int NH = 0; NH < 2; NH++)
#pragma unroll
            for (int ni = 0; ni < NI; ni++)
              acc[MH][mi][NH][ni] = mfma16(af[MH][mi][kk], bf[NH][ni][kk], acc[MH][mi][NH][ni]);
    __builtin_amdgcn_s_setprio(0);

    s = (s + 1 >= 3) ? 0 : s + 1;
  }
#undef STG

#pragma unroll
  for (int MH = 0; MH < 2; MH++)
#pragma unroll
    for (int mi = 0; mi < 2; mi++)
#pragma unroll
      for (int NH = 0; NH < 2; NH++)
#pragma unroll
        for (int ni = 0; ni < NI; ni++)
#pragma unroll
          for (int j = 0; j < 4; j++) {
            const size_t row = m0 + MH * 64 + mq + mi * 16 + frow + j;
            const size_t col = n0 + NH * (BN / 2) + nq + ni * 16 + fr;
            if (F32OUT) ((float*)Cout)[row * Nt + col] = acc[MH][mi][NH][ni][j];
            else ((u16*)Cout)[row * Nt + col] = f2bf(acc[MH][mi][NH][ni][j]);
          }
}

// ---------------- k_normKV: kv part of qgkv -> kn, vnT (q/g handled in attn) ----------------
__global__ __launch_bounds__(256, 4) void k_normKV(const u16* __restrict__ qgkv,
                                                   u16* __restrict__ kn,
                                                   u16* __restrict__ vnT) {
  __shared__ u16 vt[128 * 64];  // [d][nl], col swizzle: c' = nl ^ ((d&15)<<2)
  const int tid = threadIdx.x, lane = tid & 63, wid = tid >> 6;
  const int hb = blockIdx.y;            // b*16 + h
  const int h = hb & 15, b = hb >> 4;
  const int n0 = blockIdx.x * 64;

  for (int s = 0; s < 16; s++) {
    const int nl = wid * 16 + s;        // 0..63
    const int n = n0 + nl;
    const size_t bn = (size_t)b * 2048 + n;
    const size_t basek = bn * 6144 + 3072 + (size_t)h * 192;

    float k = bf2f(qgkv[basek + lane]);
    float v0 = bf2f(qgkv[basek + 64 + lane]);
    float v1 = bf2f(qgkv[basek + 128 + lane]);

    float ks = k * k, vs = v0 * v0 + v1 * v1;
#pragma unroll
    for (int m = 1; m < 64; m <<= 1) {
      ks += __shfl_xor(ks, m);
      vs += __shfl_xor(vs, m);
    }
    float rk = 1.f / fmaxf(sqrtf(ks), 1e-12f);
    float rv = 1.f / fmaxf(sqrtf(vs), 1e-12f);

    kn[((size_t)hb * 2048 + n) * 64 + lane] = f2bf(k * rk);

    const int d0 = lane, d1 = 64 + lane;
    vt[d0 * 64 + (nl ^ ((d0 & 15) << 2))] = f2bf(v0 * rv);
    vt[d1 * 64 + (nl ^ ((d1 & 15) << 2))] = f2bf(v1 * rv);
  }
  __syncthreads();

  // write-out: sigma(col) = swap bits 2<->3 within n&31 (preserves bits 0-1)
#pragma unroll
  for (int p = 0; p < 8; p++) {
    const int d = p * 16 + (tid >> 4);
    const int nq = (tid & 15) * 4;
    const int cb = nq ^ ((d & 15) << 2);
    const int nq2 = (nq & ~12) | ((nq & 4) << 1) | ((nq & 8) >> 1);
    ushort4 o;
    o.x = vt[d * 64 + cb + 0];
    o.y = vt[d * 64 + cb + 1];
    o.z = vt[d * 64 + cb + 2];
    o.w = vt[d * 64 + cb + 3];
    *(ushort4*)(vnT + ((size_t)hb * 128 + d) * 2048 + n0 + nq2) = o;
  }
}

// ---------------- fused screened attention (q-norm + gate fused in) ----------------
__global__ __launch_bounds__(256, 2) void k_attn(const u16* __restrict__ qgkv,
                                                 const u16* __restrict__ kn,
                                                 const u16* __restrict__ vnT,
                                                 const float* __restrict__ ls_iaw,
                                                 const float* __restrict__ ls_hws,
                                                 u16* __restrict__ pre_out) {
  extern __shared__ char smem[];
  u16* KsB = (u16*)smem;                 // [3][64 k][64 dk]   slot stride 4096 u16
  u16* VsB = (u16*)(smem + 24576);       // [3][128 d][64 k']  slot stride 8192 u16
  u16* Os = (u16*)smem;                  // epilogue reuse: [128 q][132 d] 33.8KB

  const int tid = threadIdx.x, lane = tid & 63, wid = tid >> 6;
  const int bid = blockIdx.y * 16 + blockIdx.x;
  const int bh = (bid & 7) * 4 + ((bid >> 3) & 3);
  const int n0 = (bid >> 5) * 128;
  const int h = bh & 15, b = bh >> 4;
  const int l31 = lane & 31, L = lane >> 5, rb = l31 & 7;
  const float r = 1.f / (__expf(ls_iaw[h]) + 1.f);
  const float c1 = 1.f - r;
  const float whs = __expf(ls_hws[h]);

  // Q: load raw from qgkv, normalize in-register
  const int wq = wid * 32;
  const u16* qraw = qgkv + ((size_t)b * 2048 + n0 + wq + l31) * 6144 + (size_t)h * 192;
  u16x8 qf[4];
  float ssq = 0.f;
#pragma unroll
  for (int c = 0; c < 4; c++) {
    qf[c] = *(const u16x8*)(qraw + c * 16 + L * 8);
#pragma unroll
    for (int e = 0; e < 8; e++) { float x = bf2f(qf[c][e]); ssq += x * x; }
  }
  ssq += __shfl_xor(ssq, 32);
  const float rq = 1.f / fmaxf(sqrtf(ssq), 1e-12f);
#pragma unroll
  for (int c = 0; c < 4; c++) {
    u16x8 t;
#pragma unroll
    for (int e = 0; e < 8; e++) t[e] = f2bf(bf2f(qf[c][e]) * rq);
    qf[c] = t;
  }

  f32x16 acc[4] = {};  // acc[dt]: D[d = dt*32 + (reg&3)+8*(reg>>2)+4L][q = l31]
  const u16* kbase = kn + (size_t)bh * 2048 * 64;
  const u16* vbase = vnT + (size_t)bh * 128 * 2048;

  int ks_goff[2];
#pragma unroll
  for (int i = 0; i < 2; i++) {
    int row = wid * 16 + i * 8 + (lane >> 3);
    ks_goff[i] = row * 64 + (((lane & 7) ^ (row & 7)) << 3);
  }
  int vs_goff[4];
#pragma unroll
  for (int i = 0; i < 4; i++) {
    int row = wid * 32 + i * 8 + (lane >> 3);
    vs_goff[i] = row * 2048 + (((lane & 7) ^ (row & 7)) << 3);
  }

  // prologue: stage tile 0 -> slot 0, tile 1 -> slot 1
  {
    u16* KsC0 = KsB + wid * 1024;
    u16* VsC0 = VsB + wid * 2048;
#pragma unroll
    for (int i = 0; i < 2; i++) gload_lds16(kbase + ks_goff[i], KsC0 + i * 512);
#pragma unroll
    for (int i = 0; i < 4; i++) gload_lds16(vbase + vs_goff[i], VsC0 + i * 512);
    u16* KsC1 = KsB + 4096 + wid * 1024;
    u16* VsC1 = VsB + 8192 + wid * 2048;
#pragma unroll
    for (int i = 0; i < 2; i++) gload_lds16(kbase + (size_t)64 * 64 + ks_goff[i], KsC1 + i * 512);
#pragma unroll
    for (int i = 0; i < 4; i++) gload_lds16(vbase + (size_t)vs_goff[i] + 64, VsC1 + i * 512);
  }

  int s = 0;
  for (int t = 0; t < 32; t++) {
    if (t < 31) {
      asm volatile("s_waitcnt vmcnt(6) lgkmcnt(0)" ::: "memory");
    } else {
      asm volatile("s_waitcnt vmcnt(0) lgkmcnt(0)" ::: "memory");
    }
    __builtin_amdgcn_s_barrier();
    asm volatile("" ::: "memory");

    if (t + 2 < 32) {
      const int s2 = (s + 2 >= 3) ? s - 1 : s + 2;
      const int kv0 = (t + 2) * 64;
      u16* KsC2 = KsB + s2 * 4096 + wid * 1024;
      u16* VsC2 = VsB + s2 * 8192 + wid * 2048;
#pragma unroll
      for (int i = 0; i < 2; i++) gload_lds16(kbase + (size_t)kv0 * 64 + ks_goff[i], KsC2 + i * 512);
#pragma unroll
      for (int i = 0; i < 4; i++) gload_lds16(vbase + (size_t)vs_goff[i] + kv0, VsC2 + i * 512);
    }

    const u16* KsC = KsB + s * 4096;
    const u16* VsC = VsB + s * 8192;

    f32x16 sT0 = {}, sT1 = {};
    __builtin_amdgcn_s_setprio(1);
#pragma unroll
    for (int c = 0; c < 4; c++) {
      u16x8 kf0 = *(const u16x8*)(KsC + (0 + l31) * 64 + (((2 * c + L) ^ rb) << 3));
      u16x8 kf1 = *(const u16x8*)(KsC + (32 + l31) * 64 + (((2 * c + L) ^ rb) << 3));
      sT0 = mfma32(kf0, qf[c], sT0);
      sT1 = mfma32(kf1, qf[c], sT1);
    }
    __builtin_amdgcn_s_setprio(0);

    uint32_t w[2][4][2];
#pragma unroll
    for (int m = 0; m < 4; m++)
#pragma unroll
      for (int p = 0; p < 2; p++) {
        float a0 = fmaxf(0.f, fmaf(r, sT0[4 * m + 2 * p], c1));
        float a1 = fmaxf(0.f, fmaf(r, sT0[4 * m + 2 * p + 1], c1));
        float b0 = fmaxf(0.f, fmaf(r, sT1[4 * m + 2 * p], c1));
        float b1 = fmaxf(0.f, fmaf(r, sT1[4 * m + 2 * p + 1], c1));
        w[0][m][p] = (uint32_t)f2bf(a0 * a0) | ((uint32_t)f2bf(a1 * a1) << 16);
        w[1][m][p] = (uint32_t)f2bf(b0 * b0) | ((uint32_t)f2bf(b1 * b1) << 16);
      }

    __builtin_amdgcn_s_setprio(1);
#pragma unroll
    for (int kt = 0; kt < 2; kt++)
#pragma unroll
      for (int pair = 0; pair < 2; pair++) {
        i32x4 pw;
        pw[0] = (int)w[kt][2 * pair][0];
        pw[1] = (int)w[kt][2 * pair][1];
        pw[2] = (int)w[kt][2 * pair + 1][0];
        pw[3] = (int)w[kt][2 * pair + 1][1];
        u16x8 pf = __builtin_bit_cast(u16x8, pw);
        const int chunk = 4 * kt + 2 * pair + L;
#pragma unroll
        for (int dt = 0; dt < 4; dt++) {
          u16x8 vf = *(const u16x8*)(VsC + (dt * 32 + l31) * 64 + ((chunk ^ rb) << 3));
          acc[dt] = mfma32(vf, pf, acc[dt]);
        }
      }
    __builtin_amdgcn_s_setprio(0);
    s = (s + 1 >= 3) ? 0 : s + 1;
  }

  float ss = 0.f;
#pragma unroll
  for (int dt = 0; dt < 4; dt++)
#pragma unroll
    for (int e = 0; e < 16; e++) { float x = acc[dt][e]; ss += x * x; }
  ss += __shfl_xor(ss, 32);
  float nn = sqrtf(ss);
  float scale = tanhf(nn) / fmaxf(nn, 1e-12f) * whs;

  __syncthreads();

  // epilogue: raw g from qgkv -> tanh(silu(g)) on the fly
  const int q = wq + l31;
  const size_t grow = ((size_t)b * 2048 + n0 + q) * 6144 + (size_t)h * 192 + 64;
#pragma unroll
  for (int dt = 0; dt < 4; dt++)
#pragma unroll
    for (int m = 0; m < 4; m++) {
      const int d = dt * 32 + 8 * m + 4 * L;
      ushort4 gv = *(const ushort4*)(qgkv + grow + d);
      float g0 = bf2f(gv.x), g1 = bf2f(gv.y), g2 = bf2f(gv.z), g3 = bf2f(gv.w);
      float t0 = tanhf(g0 / (1.f + __expf(-g0)));
      float t1 = tanhf(g1 / (1.f + __expf(-g1)));
      float t2 = tanhf(g2 / (1.f + __expf(-g2)));
      float t3 = tanhf(g3 / (1.f + __expf(-g3)));
      ushort4 o;
      o.x = f2bf(acc[dt][4 * m + 0] * scale * t0);
      o.y = f2bf(acc[dt][4 * m + 1] * scale * t1);
      o.z = f2bf(acc[dt][4 * m + 2] * scale * t2);
      o.w = f2bf(acc[dt][4 * m + 3] * scale * t3);
      *(ushort4*)(Os + q * 132 + d) = o;
    }
  __syncthreads();

  const int orow = tid >> 1, oc0 = (tid & 1) * 64;
  const size_t obase = ((size_t)b * 2048 + n0 + orow) * 2048 + (size_t)h * 128 + oc0;
#pragma unroll
  for (int j = 0; j < 16; j++) {
    ushort4 v = *(const ushort4*)(Os + orow * 132 + oc0 + 4 * j);
    *(ushort4*)(pre_out + obase + 4 * j) = v;
  }
}

extern "C" void kernel_launch(void* const* d_in, const int* in_sizes, int n_in,
                              void* d_out, int out_size, void* d_ws, size_t ws_size,
                              hipStream_t stream) {
  (void)in_sizes; (void)n_in; (void)out_size; (void)ws_size;
  const float* tokens = (const float*)d_in[0];
  const float* Wqg = (const float*)d_in[1];
  const float* Wkv = (const float*)d_in[2];
  const float* Wo = (const float*)d_in[3];
  const float* ls_iaw = (const float*)d_in[4];
  const float* ls_hws = (const float*)d_in[5];
  float* out = (float*)d_out;
  char* ws = (char*)d_ws;

  // workspace layout (phased aliasing):
  u16* WoT = (u16*)(ws + 0);
  char* regA = ws + 8388608;
  u16* tok_bf = (u16*)(regA);
  u16* WqgkvT = (u16*)(regA + 16777216);
  u16* kn = (u16*)(regA);
  u16* vnT = (u16*)(regA + 8388608);
  u16* pre_out = (u16*)(regA + 25165824);
  char* regB = ws + 58720256;
  u16* qgkv_raw = (u16*)(regB);

  k_cvt<<<4096, 256, 0, stream>>>(tokens, tok_bf, 8388608);
  k_cvtT<<<dim3(96, 64), 256, 0, stream>>>(Wqg, WqgkvT, 2048, 3072);
  k_cvtT<<<dim3(96, 64), 256, 0, stream>>>(Wkv, WqgkvT + (size_t)3072 * 2048, 2048, 3072);
  k_cvtT<<<dim3(64, 64), 256, 0, stream>>>(Wo, WoT, 2048, 2048);

  // merged projection: 256x384 tile, grid 256 = 1 exact round, 120KB LDS triple-buffer
  k_gemmP2<<<256, 512, 122880, stream>>>(tok_bf, WqgkvT, qgkv_raw, 6144, 2048);

  // k/v normalize only (q-norm and gate fused into attn)
  k_normKV<<<dim3(32, 32), 256, 0, stream>>>(qgkv_raw, kn, vnT);

  // attn: 72KB LDS (3-slot K/V), 2 blocks/CU; reads qgkv_raw (q,g) + kn + vnT
  k_attn<<<dim3(16, 32), 256, 73728, stream>>>(qgkv_raw, kn, vnT, ls_iaw, ls_hws, pre_out);

  // final projection: 128x256 tile, grid 256 = 1 exact round, 144KB LDS triple-buffer
  k_gemmU<2, 1><<<256, 512, 147456, stream>>>(pre_out, WoT, out, 2048, 2048);
}

// Round 17
// 256.491 us; speedup vs baseline: 1.1859x; 1.1859x over previous
//
#include <hip/hip_runtime.h>
#include <hip/hip_bf16.h>
#include <stdint.h>

// GatedScreeningTile: B=2 N=2048 DIM=2048 H=16 DK=64 DV=128 DIM_INNER=3072
// R17 = exact revert to R15 (measured best 256.4us): gemmP2 2-phase 3-slot
// counted-vmcnt; fused q-norm/gate attn; 3-slot attn + final GEMM.
// (R16's single-barrier gemmP2 regressed 107->165us: the mid barrier IS the
// interleave mechanism — splitting the ds_read burst across two MFMA clusters.)

typedef unsigned short u16;
typedef __bf16 bf16x8 __attribute__((ext_vector_type(8)));
typedef u16 u16x8 __attribute__((ext_vector_type(8)));
typedef float f32x4 __attribute__((ext_vector_type(4)));
typedef float f32x16 __attribute__((ext_vector_type(16)));
typedef int i32x4 __attribute__((ext_vector_type(4)));

#define DEVINL __device__ __forceinline__

DEVINL u16 f2bf(float f) {
  union { float f; uint32_t u; } v; v.f = f;
  uint32_t r = (v.u + 0x7FFFu + ((v.u >> 16) & 1u)) >> 16;
  return (u16)r;
}
DEVINL float bf2f(u16 x) {
  union { uint32_t u; float f; } v; v.u = ((uint32_t)x) << 16;
  return v.f;
}
DEVINL bf16x8 as_bf(u16x8 v) { return __builtin_bit_cast(bf16x8, v); }

typedef const __attribute__((address_space(1))) uint32_t* gptr_t;
typedef __attribute__((address_space(3))) uint32_t* lptr_t;
DEVINL void gload_lds16(const void* g, void* l) {
  __builtin_amdgcn_global_load_lds((gptr_t)g, (lptr_t)l, 16, 0, 0);
}

DEVINL f32x4 mfma16(u16x8 a, u16x8 b, f32x4 c) {
  return __builtin_amdgcn_mfma_f32_16x16x32_bf16(as_bf(a), as_bf(b), c, 0, 0, 0);
}
DEVINL f32x16 mfma32(u16x8 a, u16x8 b, f32x16 c) {
  return __builtin_amdgcn_mfma_f32_32x32x16_bf16(as_bf(a), as_bf(b), c, 0, 0, 0);
}

// ---------------- fp32 -> bf16 convert (same layout) ----------------
__global__ void k_cvt(const float* __restrict__ src, u16* __restrict__ dst, int n) {
  int i = (blockIdx.x * blockDim.x + threadIdx.x) * 4;
  int stride = gridDim.x * blockDim.x * 4;
  for (; i < n; i += stride) {
    float4 f = *(const float4*)(src + i);
    ushort4 o;
    o.x = f2bf(f.x); o.y = f2bf(f.y); o.z = f2bf(f.z); o.w = f2bf(f.w);
    *(ushort4*)(dst + i) = o;
  }
}

// ---------------- fp32 (RxC) -> bf16 transposed (CxR) ----------------
__global__ void k_cvtT(const float* __restrict__ src, u16* __restrict__ dst, int R, int C) {
  __shared__ float tile[32][33];
  int c0 = blockIdx.x * 32, r0 = blockIdx.y * 32;
  int tc = threadIdx.x & 31, tr = threadIdx.x >> 5;  // tr 0..7
#pragma unroll
  for (int i = 0; i < 4; i++) {
    int r = tr + i * 8;
    tile[r][tc] = src[(size_t)(r0 + r) * C + c0 + tc];
  }
  __syncthreads();
#pragma unroll
  for (int i = 0; i < 4; i++) {
    int r = tr + i * 8;  // row in dst tile (= src col)
    dst[(size_t)(c0 + r) * R + r0 + tc] = f2bf(tile[tc][r]);
  }
}

// ---------------- k_gemmP2: merged projection, 256x384, BK=32, triple-buffer ----------------
// (R12/R13-verified 2-phase: counted vmcnt(5), stage 2 tiles ahead, 120KB LDS.)
__global__ __launch_bounds__(512, 1) void k_gemmP2(const u16* __restrict__ A,
                                                   const u16* __restrict__ Bt,
                                                   u16* __restrict__ C,
                                                   int Nt, int K) {
  extern __shared__ char smem[];
  u16* As = (u16*)smem;             // [3][256][32] u16, slot stride 8192
  u16* Bs = (u16*)(smem + 49152);   // [3][384][32] u16, slot stride 12288

  const int tid = threadIdx.x, lane = tid & 63, wid = tid >> 6;

  const int bid = blockIdx.x;
  const int xcd = bid & 7, idx = bid >> 3;  // idx 0..31
  const int m0 = (idx & 15) * 256;
  const int n0 = (xcd * 2 + (idx >> 4)) * 384;

  const int wm = (wid >> 2) * 128, wn = (wid & 3) * 96;
  const int fr = lane & 15, hi = lane >> 4, frow = hi * 4;
  const int kg = (fr >> 1) & 3;

  f32x4 acc[2][4][6] = {};

  const int sg = ((lane & 3) ^ ((lane >> 3) & 3)) << 3;
  const int srow = wid * 16 + (lane >> 2);
  const u16* gA0 = A + (size_t)(m0 + srow) * K + sg;
  const u16* gB0 = Bt + (size_t)(n0 + srow) * K + sg;
  const size_t r128 = (size_t)128 * K;
  const int dwave = wid * 512;

#define SA(S, I, KT) gload_lds16(gA0 + (size_t)(I) * r128 + (KT), As + (S) * 8192 + (I) * 4096 + dwave)
#define SB(S, I, KT) gload_lds16(gB0 + (size_t)(I) * r128 + (KT), Bs + (S) * 12288 + (I) * 4096 + dwave)

  SA(0, 0, 0); SA(0, 1, 0); SB(0, 0, 0); SB(0, 1, 0); SB(0, 2, 0);
  SA(1, 0, 32); SA(1, 1, 32); SB(1, 0, 32); SB(1, 1, 32); SB(1, 2, 32);

  const int NTI = K >> 5;  // 64
  int s = 0;
  for (int t = 0; t < NTI; t++) {
    const int s2 = (s + 2 >= 3) ? s - 1 : s + 2;
    const int ktn = (t + 2) << 5;
    const bool do_stage = (t + 2) < NTI;

    if (t < NTI - 1) {
      asm volatile("s_waitcnt vmcnt(5)" ::: "memory");
    } else {
      asm volatile("s_waitcnt vmcnt(0)" ::: "memory");
    }
    __builtin_amdgcn_s_barrier();
    asm volatile("" ::: "memory");

    const u16* Ab = As + s * 8192;
    const u16* Bb = Bs + s * 12288;

    u16x8 bf[6];
#pragma unroll
    for (int nj = 0; nj < 6; nj++)
      bf[nj] = *(const u16x8*)(Bb + (wn + nj * 16 + fr) * 32 + ((hi ^ kg) << 3));
    u16x8 af[4];
#pragma unroll
    for (int mi = 0; mi < 4; mi++)
      af[mi] = *(const u16x8*)(Ab + (wm + mi * 16 + fr) * 32 + ((hi ^ kg) << 3));
    if (do_stage) { SA(s2, 0, ktn); SA(s2, 1, ktn); SB(s2, 0, ktn); }
    __builtin_amdgcn_s_setprio(1);
#pragma unroll
    for (int mi = 0; mi < 4; mi++)
#pragma unroll
      for (int nj = 0; nj < 6; nj++)
        acc[0][mi][nj] = mfma16(af[mi], bf[nj], acc[0][mi][nj]);
    __builtin_amdgcn_s_setprio(0);

    __builtin_amdgcn_s_barrier();
    asm volatile("" ::: "memory");
#pragma unroll
    for (int mi = 0; mi < 4; mi++)
      af[mi] = *(const u16x8*)(Ab + (wm + 64 + mi * 16 + fr) * 32 + ((hi ^ kg) << 3));
    if (do_stage) { SB(s2, 1, ktn); SB(s2, 2, ktn); }
    __builtin_amdgcn_s_setprio(1);
#pragma unroll
    for (int mi = 0; mi < 4; mi++)
#pragma unroll
      for (int nj = 0; nj < 6; nj++)
        acc[1][mi][nj] = mfma16(af[mi], bf[nj], acc[1][mi][nj]);
    __builtin_amdgcn_s_setprio(0);

    s = (s + 1 >= 3) ? 0 : s + 1;
  }
#undef SA
#undef SB

#pragma unroll
  for (int mh = 0; mh < 2; mh++)
#pragma unroll
    for (int mi = 0; mi < 4; mi++)
#pragma unroll
      for (int nj = 0; nj < 6; nj++)
#pragma unroll
        for (int j = 0; j < 4; j++) {
          const size_t row = m0 + wm + mh * 64 + mi * 16 + frow + j;
          const size_t col = n0 + wn + nj * 16 + fr;
          C[row * Nt + col] = f2bf(acc[mh][mi][nj][j]);
        }
}

// ---------------- k_gemmU: final projection (grid 256, TRIPLE-buffer, counted vmcnt) ----------------
template <int NI, int F32OUT>
__global__ __launch_bounds__(512, 1) void k_gemmU(const u16* __restrict__ A,
                                                  const u16* __restrict__ Bt,
                                                  void* __restrict__ Cout,
                                                  int Nt, int K) {
  constexpr int BN = NI * 128;
  constexpr int NLB = BN / 64;
  constexpr int ABUF = 128 * 64;
  constexpr int BBUF = BN * 64;
  extern __shared__ char smem[];
  u16* As = (u16*)smem;                   // [3][128][64]
  u16* Bs = (u16*)(smem + 3 * ABUF * 2);  // [3][BN][64]

  const int tid = threadIdx.x, lane = tid & 63, wid = tid >> 6;

  const int NPN = Nt / BN;
  const int bid = blockIdx.x;
  const int xcd = bid & 7, idx = bid >> 3;
  const int npx = NPN >> 3;
  const int m0 = (idx & 31) * 128;
  const int n0 = (xcd * npx + (idx >> 5)) * BN;

  const int mq = (wid >> 2) * 32, nq = (wid & 3) * (BN / 8);
  const int fr = lane & 15, hi = lane >> 4, frow = hi * 4, rb7 = fr & 7;

  f32x4 acc[2][2][2][NI] = {};

  const int schunk = ((lane & 7) ^ ((lane >> 3) & 7)) << 3;
  const int srow = wid * 8 + (lane >> 3);
  const u16* ga0 = A + (size_t)(m0 + srow) * K + schunk;
  const u16* gb0 = Bt + (size_t)(n0 + srow) * K + schunk;
  const size_t l64 = (size_t)64 * K;
  const int dwave = wid * 512;

#define STG(T, S)                                                                     \
  {                                                                                   \
    const int kt_ = (T) << 6;                                                         \
    _Pragma("unroll") for (int i = 0; i < 2; i++)                                     \
        gload_lds16(ga0 + (size_t)i * l64 + kt_, As + (S) * ABUF + i * 4096 + dwave); \
    _Pragma("unroll") for (int i = 0; i < NLB; i++)                                   \
        gload_lds16(gb0 + (size_t)i * l64 + kt_, Bs + (S) * BBUF + i * 4096 + dwave); \
  }

  STG(0, 0);
  STG(1, 1);

  const int NTI = K >> 6;
  int s = 0;
  for (int t = 0; t < NTI; t++) {
    if (t < NTI - 1) {
      if constexpr (NI == 2) asm volatile("s_waitcnt vmcnt(6) lgkmcnt(0)" ::: "memory");
      else asm volatile("s_waitcnt vmcnt(8) lgkmcnt(0)" ::: "memory");
    } else {
      asm volatile("s_waitcnt vmcnt(0) lgkmcnt(0)" ::: "memory");
    }
    __builtin_amdgcn_s_barrier();
    asm volatile("" ::: "memory");

    if (t + 2 < NTI) {
      const int s2 = (s + 2 >= 3) ? s - 1 : s + 2;
      STG(t + 2, s2);
    }

    const u16* Ab = As + s * ABUF;
    const u16* Bb = Bs + s * BBUF;

    u16x8 af[2][2][2], bf[2][NI][2];
#pragma unroll
    for (int MH = 0; MH < 2; MH++)
#pragma unroll
      for (int mi = 0; mi < 2; mi++)
#pragma unroll
        for (int kk = 0; kk < 2; kk++) {
          const int row = MH * 64 + mq + mi * 16 + fr;
          af[MH][mi][kk] = *(const u16x8*)(Ab + row * 64 + (((kk * 4 + hi) ^ rb7) << 3));
        }
#pragma unroll
    for (int NH = 0; NH < 2; NH++)
#pragma unroll
      for (int ni = 0; ni < NI; ni++)
#pragma unroll
        for (int kk = 0; kk < 2; kk++) {
          const int row = NH * (BN / 2) + nq + ni * 16 + fr;
          bf[NH][ni][kk] = *(const u16x8*)(Bb + row * 64 + (((kk * 4 + hi) ^ rb7) << 3));
        }

    __builtin_amdgcn_s_setprio(1);
#pragma unroll
    for (int kk = 0; kk < 2; kk++)
#pragma unroll
      for (int MH = 0; MH < 2; MH++)
#pragma unroll
        for (int mi = 0; mi < 2; mi++)
#pragma unroll
          for (int NH = 0; NH < 2; NH++)
#pragma unroll
            for (int ni = 0; ni < NI; ni++)
              acc[MH][mi][NH][ni] = mfma16(af[MH][mi][kk], bf[NH][ni][kk], acc[MH][mi][NH][ni]);
    __builtin_amdgcn_s_setprio(0);

    s = (s + 1 >= 3) ? 0 : s + 1;
  }
#undef STG

#pragma unroll
  for (int MH = 0; MH < 2; MH++)
#pragma unroll
    for (int mi = 0; mi < 2; mi++)
#pragma unroll
      for (int NH = 0; NH < 2; NH++)
#pragma unroll
        for (int ni = 0; ni < NI; ni++)
#pragma unroll
          for (int j = 0; j < 4; j++) {
            const size_t row = m0 + MH * 64 + mq + mi * 16 + frow + j;
            const size_t col = n0 + NH * (BN / 2) + nq + ni * 16 + fr;
            if (F32OUT) ((float*)Cout)[row * Nt + col] = acc[MH][mi][NH][ni][j];
            else ((u16*)Cout)[row * Nt + col] = f2bf(acc[MH][mi][NH][ni][j]);
          }
}

// ---------------- k_normKV: kv part of qgkv -> kn, vnT (q/g handled in attn) ----------------
__global__ __launch_bounds__(256, 4) void k_normKV(const u16* __restrict__ qgkv,
                                                   u16* __restrict__ kn,
                                                   u16* __restrict__ vnT) {
  __shared__ u16 vt[128 * 64];  // [d][nl], col swizzle: c' = nl ^ ((d&15)<<2)
  const int tid = threadIdx.x, lane = tid & 63, wid = tid >> 6;
  const int hb = blockIdx.y;            // b*16 + h
  const int h = hb & 15, b = hb >> 4;
  const int n0 = blockIdx.x * 64;

  for (int s = 0; s < 16; s++) {
    const int nl = wid * 16 + s;        // 0..63
    const int n = n0 + nl;
    const size_t bn = (size_t)b * 2048 + n;
    const size_t basek = bn * 6144 + 3072 + (size_t)h * 192;

    float k = bf2f(qgkv[basek + lane]);
    float v0 = bf2f(qgkv[basek + 64 + lane]);
    float v1 = bf2f(qgkv[basek + 128 + lane]);

    float ks = k * k, vs = v0 * v0 + v1 * v1;
#pragma unroll
    for (int m = 1; m < 64; m <<= 1) {
      ks += __shfl_xor(ks, m);
      vs += __shfl_xor(vs, m);
    }
    float rk = 1.f / fmaxf(sqrtf(ks), 1e-12f);
    float rv = 1.f / fmaxf(sqrtf(vs), 1e-12f);

    kn[((size_t)hb * 2048 + n) * 64 + lane] = f2bf(k * rk);

    const int d0 = lane, d1 = 64 + lane;
    vt[d0 * 64 + (nl ^ ((d0 & 15) << 2))] = f2bf(v0 * rv);
    vt[d1 * 64 + (nl ^ ((d1 & 15) << 2))] = f2bf(v1 * rv);
  }
  __syncthreads();

  // write-out: sigma(col) = swap bits 2<->3 within n&31 (preserves bits 0-1)
#pragma unroll
  for (int p = 0; p < 8; p++) {
    const int d = p * 16 + (tid >> 4);
    const int nq = (tid & 15) * 4;
    const int cb = nq ^ ((d & 15) << 2);
    const int nq2 = (nq & ~12) | ((nq & 4) << 1) | ((nq & 8) >> 1);
    ushort4 o;
    o.x = vt[d * 64 + cb + 0];
    o.y = vt[d * 64 + cb + 1];
    o.z = vt[d * 64 + cb + 2];
    o.w = vt[d * 64 + cb + 3];
    *(ushort4*)(vnT + ((size_t)hb * 128 + d) * 2048 + n0 + nq2) = o;
  }
}

// ---------------- fused screened attention (q-norm + gate fused in) ----------------
__global__ __launch_bounds__(256, 2) void k_attn(const u16* __restrict__ qgkv,
                                                 const u16* __restrict__ kn,
                                                 const u16* __restrict__ vnT,
                                                 const float* __restrict__ ls_iaw,
                                                 const float* __restrict__ ls_hws,
                                                 u16* __restrict__ pre_out) {
  extern __shared__ char smem[];
  u16* KsB = (u16*)smem;                 // [3][64 k][64 dk]   slot stride 4096 u16
  u16* VsB = (u16*)(smem + 24576);       // [3][128 d][64 k']  slot stride 8192 u16
  u16* Os = (u16*)smem;                  // epilogue reuse: [128 q][132 d] 33.8KB

  const int tid = threadIdx.x, lane = tid & 63, wid = tid >> 6;
  const int bid = blockIdx.y * 16 + blockIdx.x;
  const int bh = (bid & 7) * 4 + ((bid >> 3) & 3);
  const int n0 = (bid >> 5) * 128;
  const int h = bh & 15, b = bh >> 4;
  const int l31 = lane & 31, L = lane >> 5, rb = l31 & 7;
  const float r = 1.f / (__expf(ls_iaw[h]) + 1.f);
  const float c1 = 1.f - r;
  const float whs = __expf(ls_hws[h]);

  // Q: load raw from qgkv, normalize in-register
  const int wq = wid * 32;
  const u16* qraw = qgkv + ((size_t)b * 2048 + n0 + wq + l31) * 6144 + (size_t)h * 192;
  u16x8 qf[4];
  float ssq = 0.f;
#pragma unroll
  for (int c = 0; c < 4; c++) {
    qf[c] = *(const u16x8*)(qraw + c * 16 + L * 8);
#pragma unroll
    for (int e = 0; e < 8; e++) { float x = bf2f(qf[c][e]); ssq += x * x; }
  }
  ssq += __shfl_xor(ssq, 32);
  const float rq = 1.f / fmaxf(sqrtf(ssq), 1e-12f);
#pragma unroll
  for (int c = 0; c < 4; c++) {
    u16x8 t;
#pragma unroll
    for (int e = 0; e < 8; e++) t[e] = f2bf(bf2f(qf[c][e]) * rq);
    qf[c] = t;
  }

  f32x16 acc[4] = {};  // acc[dt]: D[d = dt*32 + (reg&3)+8*(reg>>2)+4L][q = l31]
  const u16* kbase = kn + (size_t)bh * 2048 * 64;
  const u16* vbase = vnT + (size_t)bh * 128 * 2048;

  int ks_goff[2];
#pragma unroll
  for (int i = 0; i < 2; i++) {
    int row = wid * 16 + i * 8 + (lane >> 3);
    ks_goff[i] = row * 64 + (((lane & 7) ^ (row & 7)) << 3);
  }
  int vs_goff[4];
#pragma unroll
  for (int i = 0; i < 4; i++) {
    int row = wid * 32 + i * 8 + (lane >> 3);
    vs_goff[i] = row * 2048 + (((lane & 7) ^ (row & 7)) << 3);
  }

  // prologue: stage tile 0 -> slot 0, tile 1 -> slot 1
  {
    u16* KsC0 = KsB + wid * 1024;
    u16* VsC0 = VsB + wid * 2048;
#pragma unroll
    for (int i = 0; i < 2; i++) gload_lds16(kbase + ks_goff[i], KsC0 + i * 512);
#pragma unroll
    for (int i = 0; i < 4; i++) gload_lds16(vbase + vs_goff[i], VsC0 + i * 512);
    u16* KsC1 = KsB + 4096 + wid * 1024;
    u16* VsC1 = VsB + 8192 + wid * 2048;
#pragma unroll
    for (int i = 0; i < 2; i++) gload_lds16(kbase + (size_t)64 * 64 + ks_goff[i], KsC1 + i * 512);
#pragma unroll
    for (int i = 0; i < 4; i++) gload_lds16(vbase + (size_t)vs_goff[i] + 64, VsC1 + i * 512);
  }

  int s = 0;
  for (int t = 0; t < 32; t++) {
    if (t < 31) {
      asm volatile("s_waitcnt vmcnt(6) lgkmcnt(0)" ::: "memory");
    } else {
      asm volatile("s_waitcnt vmcnt(0) lgkmcnt(0)" ::: "memory");
    }
    __builtin_amdgcn_s_barrier();
    asm volatile("" ::: "memory");

    if (t + 2 < 32) {
      const int s2 = (s + 2 >= 3) ? s - 1 : s + 2;
      const int kv0 = (t + 2) * 64;
      u16* KsC2 = KsB + s2 * 4096 + wid * 1024;
      u16* VsC2 = VsB + s2 * 8192 + wid * 2048;
#pragma unroll
      for (int i = 0; i < 2; i++) gload_lds16(kbase + (size_t)kv0 * 64 + ks_goff[i], KsC2 + i * 512);
#pragma unroll
      for (int i = 0; i < 4; i++) gload_lds16(vbase + (size_t)vs_goff[i] + kv0, VsC2 + i * 512);
    }

    const u16* KsC = KsB + s * 4096;
    const u16* VsC = VsB + s * 8192;

    f32x16 sT0 = {}, sT1 = {};
    __builtin_amdgcn_s_setprio(1);
#pragma unroll
    for (int c = 0; c < 4; c++) {
      u16x8 kf0 = *(const u16x8*)(KsC + (0 + l31) * 64 + (((2 * c + L) ^ rb) << 3));
      u16x8 kf1 = *(const u16x8*)(KsC + (32 + l31) * 64 + (((2 * c + L) ^ rb) << 3));
      sT0 = mfma32(kf0, qf[c], sT0);
      sT1 = mfma32(kf1, qf[c], sT1);
    }
    __builtin_amdgcn_s_setprio(0);

    uint32_t w[2][4][2];
#pragma unroll
    for (int m = 0; m < 4; m++)
#pragma unroll
      for (int p = 0; p < 2; p++) {
        float a0 = fmaxf(0.f, fmaf(r, sT0[4 * m + 2 * p], c1));
        float a1 = fmaxf(0.f, fmaf(r, sT0[4 * m + 2 * p + 1], c1));
        float b0 = fmaxf(0.f, fmaf(r, sT1[4 * m + 2 * p], c1));
        float b1 = fmaxf(0.f, fmaf(r, sT1[4 * m + 2 * p + 1], c1));
        w[0][m][p] = (uint32_t)f2bf(a0 * a0) | ((uint32_t)f2bf(a1 * a1) << 16);
        w[1][m][p] = (uint32_t)f2bf(b0 * b0) | ((uint32_t)f2bf(b1 * b1) << 16);
      }

    __builtin_amdgcn_s_setprio(1);
#pragma unroll
    for (int kt = 0; kt < 2; kt++)
#pragma unroll
      for (int pair = 0; pair < 2; pair++) {
        i32x4 pw;
        pw[0] = (int)w[kt][2 * pair][0];
        pw[1] = (int)w[kt][2 * pair][1];
        pw[2] = (int)w[kt][2 * pair + 1][0];
        pw[3] = (int)w[kt][2 * pair + 1][1];
        u16x8 pf = __builtin_bit_cast(u16x8, pw);
        const int chunk = 4 * kt + 2 * pair + L;
#pragma unroll
        for (int dt = 0; dt < 4; dt++) {
          u16x8 vf = *(const u16x8*)(VsC + (dt * 32 + l31) * 64 + ((chunk ^ rb) << 3));
          acc[dt] = mfma32(vf, pf, acc[dt]);
        }
      }
    __builtin_amdgcn_s_setprio(0);
    s = (s + 1 >= 3) ? 0 : s + 1;
  }

  float ss = 0.f;
#pragma unroll
  for (int dt = 0; dt < 4; dt++)
#pragma unroll
    for (int e = 0; e < 16; e++) { float x = acc[dt][e]; ss += x * x; }
  ss += __shfl_xor(ss, 32);
  float nn = sqrtf(ss);
  float scale = tanhf(nn) / fmaxf(nn, 1e-12f) * whs;

  __syncthreads();

  // epilogue: raw g from qgkv -> tanh(silu(g)) on the fly
  const int q = wq + l31;
  const size_t grow = ((size_t)b * 2048 + n0 + q) * 6144 + (size_t)h * 192 + 64;
#pragma unroll
  for (int dt = 0; dt < 4; dt++)
#pragma unroll
    for (int m = 0; m < 4; m++) {
      const int d = dt * 32 + 8 * m + 4 * L;
      ushort4 gv = *(const ushort4*)(qgkv + grow + d);
      float g0 = bf2f(gv.x), g1 = bf2f(gv.y), g2 = bf2f(gv.z), g3 = bf2f(gv.w);
      float t0 = tanhf(g0 / (1.f + __expf(-g0)));
      float t1 = tanhf(g1 / (1.f + __expf(-g1)));
      float t2 = tanhf(g2 / (1.f + __expf(-g2)));
      float t3 = tanhf(g3 / (1.f + __expf(-g3)));
      ushort4 o;
      o.x = f2bf(acc[dt][4 * m + 0] * scale * t0);
      o.y = f2bf(acc[dt][4 * m + 1] * scale * t1);
      o.z = f2bf(acc[dt][4 * m + 2] * scale * t2);
      o.w = f2bf(acc[dt][4 * m + 3] * scale * t3);
      *(ushort4*)(Os + q * 132 + d) = o;
    }
  __syncthreads();

  const int orow = tid >> 1, oc0 = (tid & 1) * 64;
  const size_t obase = ((size_t)b * 2048 + n0 + orow) * 2048 + (size_t)h * 128 + oc0;
#pragma unroll
  for (int j = 0; j < 16; j++) {
    ushort4 v = *(const ushort4*)(Os + orow * 132 + oc0 + 4 * j);
    *(ushort4*)(pre_out + obase + 4 * j) = v;
  }
}

extern "C" void kernel_launch(void* const* d_in, const int* in_sizes, int n_in,
                              void* d_out, int out_size, void* d_ws, size_t ws_size,
                              hipStream_t stream) {
  (void)in_sizes; (void)n_in; (void)out_size; (void)ws_size;
  const float* tokens = (const float*)d_in[0];
  const float* Wqg = (const float*)d_in[1];
  const float* Wkv = (const float*)d_in[2];
  const float* Wo = (const float*)d_in[3];
  const float* ls_iaw = (const float*)d_in[4];
  const float* ls_hws = (const float*)d_in[5];
  float* out = (float*)d_out;
  char* ws = (char*)d_ws;

  // workspace layout (phased aliasing):
  u16* WoT = (u16*)(ws + 0);
  char* regA = ws + 8388608;
  u16* tok_bf = (u16*)(regA);
  u16* WqgkvT = (u16*)(regA + 16777216);
  u16* kn = (u16*)(regA);
  u16* vnT = (u16*)(regA + 8388608);
  u16* pre_out = (u16*)(regA + 25165824);
  char* regB = ws + 58720256;
  u16* qgkv_raw = (u16*)(regB);

  k_cvt<<<4096, 256, 0, stream>>>(tokens, tok_bf, 8388608);
  k_cvtT<<<dim3(96, 64), 256, 0, stream>>>(Wqg, WqgkvT, 2048, 3072);
  k_cvtT<<<dim3(96, 64), 256, 0, stream>>>(Wkv, WqgkvT + (size_t)3072 * 2048, 2048, 3072);
  k_cvtT<<<dim3(64, 64), 256, 0, stream>>>(Wo, WoT, 2048, 2048);

  // merged projection: 256x384 tile, grid 256 = 1 exact round, 120KB LDS triple-buffer
  k_gemmP2<<<256, 512, 122880, stream>>>(tok_bf, WqgkvT, qgkv_raw, 6144, 2048);

  // k/v normalize only (q-norm and gate fused into attn)
  k_normKV<<<dim3(32, 32), 256, 0, stream>>>(qgkv_raw, kn, vnT);

  // attn: 72KB LDS (3-slot K/V), 2 blocks/CU; reads qgkv_raw (q,g) + kn + vnT
  k_attn<<<dim3(16, 32), 256, 73728, stream>>>(qgkv_raw, kn, vnT, ls_iaw, ls_hws, pre_out);

  // final projection: 128x256 tile, grid 256 = 1 exact round, 144KB LDS triple-buffer
  k_gemmU<2, 1><<<256, 512, 147456, stream>>>(pre_out, WoT, out, 2048, 2048);
}

// Round 18
// 251.302 us; speedup vs baseline: 1.2104x; 1.0206x over previous
//
#include <hip/hip_runtime.h>
#include <hip/hip_bf16.h>
#include <stdint.h>

// GatedScreeningTile: B=2 N=2048 DIM=2048 H=16 DK=64 DV=128 DIM_INNER=3072
// R18 = R17 + attn screen-pack via hardware v_cvt_pk_bf16_f32 (replaces ~7-op
// manual bf16 pair-pack; attn was VALU-bound: VALUBusy 28.7% vs MfmaUtil 15.6%).

typedef unsigned short u16;
typedef __bf16 bf16x8 __attribute__((ext_vector_type(8)));
typedef u16 u16x8 __attribute__((ext_vector_type(8)));
typedef float f32x4 __attribute__((ext_vector_type(4)));
typedef float f32x16 __attribute__((ext_vector_type(16)));
typedef int i32x4 __attribute__((ext_vector_type(4)));

#define DEVINL __device__ __forceinline__

DEVINL u16 f2bf(float f) {
  union { float f; uint32_t u; } v; v.f = f;
  uint32_t r = (v.u + 0x7FFFu + ((v.u >> 16) & 1u)) >> 16;
  return (u16)r;
}
DEVINL float bf2f(u16 x) {
  union { uint32_t u; float f; } v; v.u = ((uint32_t)x) << 16;
  return v.f;
}
DEVINL bf16x8 as_bf(u16x8 v) { return __builtin_bit_cast(bf16x8, v); }

DEVINL uint32_t cvt_pk_bf16(float lo, float hi) {
  uint32_t r;
  asm("v_cvt_pk_bf16_f32 %0, %1, %2" : "=v"(r) : "v"(lo), "v"(hi));
  return r;
}

typedef const __attribute__((address_space(1))) uint32_t* gptr_t;
typedef __attribute__((address_space(3))) uint32_t* lptr_t;
DEVINL void gload_lds16(const void* g, void* l) {
  __builtin_amdgcn_global_load_lds((gptr_t)g, (lptr_t)l, 16, 0, 0);
}

DEVINL f32x4 mfma16(u16x8 a, u16x8 b, f32x4 c) {
  return __builtin_amdgcn_mfma_f32_16x16x32_bf16(as_bf(a), as_bf(b), c, 0, 0, 0);
}
DEVINL f32x16 mfma32(u16x8 a, u16x8 b, f32x16 c) {
  return __builtin_amdgcn_mfma_f32_32x32x16_bf16(as_bf(a), as_bf(b), c, 0, 0, 0);
}

// ---------------- fp32 -> bf16 convert (same layout) ----------------
__global__ void k_cvt(const float* __restrict__ src, u16* __restrict__ dst, int n) {
  int i = (blockIdx.x * blockDim.x + threadIdx.x) * 4;
  int stride = gridDim.x * blockDim.x * 4;
  for (; i < n; i += stride) {
    float4 f = *(const float4*)(src + i);
    ushort4 o;
    o.x = f2bf(f.x); o.y = f2bf(f.y); o.z = f2bf(f.z); o.w = f2bf(f.w);
    *(ushort4*)(dst + i) = o;
  }
}

// ---------------- fp32 (RxC) -> bf16 transposed (CxR) ----------------
__global__ void k_cvtT(const float* __restrict__ src, u16* __restrict__ dst, int R, int C) {
  __shared__ float tile[32][33];
  int c0 = blockIdx.x * 32, r0 = blockIdx.y * 32;
  int tc = threadIdx.x & 31, tr = threadIdx.x >> 5;  // tr 0..7
#pragma unroll
  for (int i = 0; i < 4; i++) {
    int r = tr + i * 8;
    tile[r][tc] = src[(size_t)(r0 + r) * C + c0 + tc];
  }
  __syncthreads();
#pragma unroll
  for (int i = 0; i < 4; i++) {
    int r = tr + i * 8;  // row in dst tile (= src col)
    dst[(size_t)(c0 + r) * R + r0 + tc] = f2bf(tile[tc][r]);
  }
}

// ---------------- k_gemmP2: merged projection, 256x384, BK=32, triple-buffer ----------------
// (R12/R13-verified 2-phase: counted vmcnt(5), stage 2 tiles ahead, 120KB LDS.)
__global__ __launch_bounds__(512, 1) void k_gemmP2(const u16* __restrict__ A,
                                                   const u16* __restrict__ Bt,
                                                   u16* __restrict__ C,
                                                   int Nt, int K) {
  extern __shared__ char smem[];
  u16* As = (u16*)smem;             // [3][256][32] u16, slot stride 8192
  u16* Bs = (u16*)(smem + 49152);   // [3][384][32] u16, slot stride 12288

  const int tid = threadIdx.x, lane = tid & 63, wid = tid >> 6;

  const int bid = blockIdx.x;
  const int xcd = bid & 7, idx = bid >> 3;  // idx 0..31
  const int m0 = (idx & 15) * 256;
  const int n0 = (xcd * 2 + (idx >> 4)) * 384;

  const int wm = (wid >> 2) * 128, wn = (wid & 3) * 96;
  const int fr = lane & 15, hi = lane >> 4, frow = hi * 4;
  const int kg = (fr >> 1) & 3;

  f32x4 acc[2][4][6] = {};

  const int sg = ((lane & 3) ^ ((lane >> 3) & 3)) << 3;
  const int srow = wid * 16 + (lane >> 2);
  const u16* gA0 = A + (size_t)(m0 + srow) * K + sg;
  const u16* gB0 = Bt + (size_t)(n0 + srow) * K + sg;
  const size_t r128 = (size_t)128 * K;
  const int dwave = wid * 512;

#define SA(S, I, KT) gload_lds16(gA0 + (size_t)(I) * r128 + (KT), As + (S) * 8192 + (I) * 4096 + dwave)
#define SB(S, I, KT) gload_lds16(gB0 + (size_t)(I) * r128 + (KT), Bs + (S) * 12288 + (I) * 4096 + dwave)

  SA(0, 0, 0); SA(0, 1, 0); SB(0, 0, 0); SB(0, 1, 0); SB(0, 2, 0);
  SA(1, 0, 32); SA(1, 1, 32); SB(1, 0, 32); SB(1, 1, 32); SB(1, 2, 32);

  const int NTI = K >> 5;  // 64
  int s = 0;
  for (int t = 0; t < NTI; t++) {
    const int s2 = (s + 2 >= 3) ? s - 1 : s + 2;
    const int ktn = (t + 2) << 5;
    const bool do_stage = (t + 2) < NTI;

    if (t < NTI - 1) {
      asm volatile("s_waitcnt vmcnt(5)" ::: "memory");
    } else {
      asm volatile("s_waitcnt vmcnt(0)" ::: "memory");
    }
    __builtin_amdgcn_s_barrier();
    asm volatile("" ::: "memory");

    const u16* Ab = As + s * 8192;
    const u16* Bb = Bs + s * 12288;

    u16x8 bf[6];
#pragma unroll
    for (int nj = 0; nj < 6; nj++)
      bf[nj] = *(const u16x8*)(Bb + (wn + nj * 16 + fr) * 32 + ((hi ^ kg) << 3));
    u16x8 af[4];
#pragma unroll
    for (int mi = 0; mi < 4; mi++)
      af[mi] = *(const u16x8*)(Ab + (wm + mi * 16 + fr) * 32 + ((hi ^ kg) << 3));
    if (do_stage) { SA(s2, 0, ktn); SA(s2, 1, ktn); SB(s2, 0, ktn); }
    __builtin_amdgcn_s_setprio(1);
#pragma unroll
    for (int mi = 0; mi < 4; mi++)
#pragma unroll
      for (int nj = 0; nj < 6; nj++)
        acc[0][mi][nj] = mfma16(af[mi], bf[nj], acc[0][mi][nj]);
    __builtin_amdgcn_s_setprio(0);

    __builtin_amdgcn_s_barrier();
    asm volatile("" ::: "memory");
#pragma unroll
    for (int mi = 0; mi < 4; mi++)
      af[mi] = *(const u16x8*)(Ab + (wm + 64 + mi * 16 + fr) * 32 + ((hi ^ kg) << 3));
    if (do_stage) { SB(s2, 1, ktn); SB(s2, 2, ktn); }
    __builtin_amdgcn_s_setprio(1);
#pragma unroll
    for (int mi = 0; mi < 4; mi++)
#pragma unroll
      for (int nj = 0; nj < 6; nj++)
        acc[1][mi][nj] = mfma16(af[mi], bf[nj], acc[1][mi][nj]);
    __builtin_amdgcn_s_setprio(0);

    s = (s + 1 >= 3) ? 0 : s + 1;
  }
#undef SA
#undef SB

#pragma unroll
  for (int mh = 0; mh < 2; mh++)
#pragma unroll
    for (int mi = 0; mi < 4; mi++)
#pragma unroll
      for (int nj = 0; nj < 6; nj++)
#pragma unroll
        for (int j = 0; j < 4; j++) {
          const size_t row = m0 + wm + mh * 64 + mi * 16 + frow + j;
          const size_t col = n0 + wn + nj * 16 + fr;
          C[row * Nt + col] = f2bf(acc[mh][mi][nj][j]);
        }
}

// ---------------- k_gemmU: final projection (grid 256, TRIPLE-buffer, counted vmcnt) ----------------
template <int NI, int F32OUT>
__global__ __launch_bounds__(512, 1) void k_gemmU(const u16* __restrict__ A,
                                                  const u16* __restrict__ Bt,
                                                  void* __restrict__ Cout,
                                                  int Nt, int K) {
  constexpr int BN = NI * 128;
  constexpr int NLB = BN / 64;
  constexpr int ABUF = 128 * 64;
  constexpr int BBUF = BN * 64;
  extern __shared__ char smem[];
  u16* As = (u16*)smem;                   // [3][128][64]
  u16* Bs = (u16*)(smem + 3 * ABUF * 2);  // [3][BN][64]

  const int tid = threadIdx.x, lane = tid & 63, wid = tid >> 6;

  const int NPN = Nt / BN;
  const int bid = blockIdx.x;
  const int xcd = bid & 7, idx = bid >> 3;
  const int npx = NPN >> 3;
  const int m0 = (idx & 31) * 128;
  const int n0 = (xcd * npx + (idx >> 5)) * BN;

  const int mq = (wid >> 2) * 32, nq = (wid & 3) * (BN / 8);
  const int fr = lane & 15, hi = lane >> 4, frow = hi * 4, rb7 = fr & 7;

  f32x4 acc[2][2][2][NI] = {};

  const int schunk = ((lane & 7) ^ ((lane >> 3) & 7)) << 3;
  const int srow = wid * 8 + (lane >> 3);
  const u16* ga0 = A + (size_t)(m0 + srow) * K + schunk;
  const u16* gb0 = Bt + (size_t)(n0 + srow) * K + schunk;
  const size_t l64 = (size_t)64 * K;
  const int dwave = wid * 512;

#define STG(T, S)                                                                     \
  {                                                                                   \
    const int kt_ = (T) << 6;                                                         \
    _Pragma("unroll") for (int i = 0; i < 2; i++)                                     \
        gload_lds16(ga0 + (size_t)i * l64 + kt_, As + (S) * ABUF + i * 4096 + dwave); \
    _Pragma("unroll") for (int i = 0; i < NLB; i++)                                   \
        gload_lds16(gb0 + (size_t)i * l64 + kt_, Bs + (S) * BBUF + i * 4096 + dwave); \
  }

  STG(0, 0);
  STG(1, 1);

  const int NTI = K >> 6;
  int s = 0;
  for (int t = 0; t < NTI; t++) {
    if (t < NTI - 1) {
      if constexpr (NI == 2) asm volatile("s_waitcnt vmcnt(6) lgkmcnt(0)" ::: "memory");
      else asm volatile("s_waitcnt vmcnt(8) lgkmcnt(0)" ::: "memory");
    } else {
      asm volatile("s_waitcnt vmcnt(0) lgkmcnt(0)" ::: "memory");
    }
    __builtin_amdgcn_s_barrier();
    asm volatile("" ::: "memory");

    if (t + 2 < NTI) {
      const int s2 = (s + 2 >= 3) ? s - 1 : s + 2;
      STG(t + 2, s2);
    }

    const u16* Ab = As + s * ABUF;
    const u16* Bb = Bs + s * BBUF;

    u16x8 af[2][2][2], bf[2][NI][2];
#pragma unroll
    for (int MH = 0; MH < 2; MH++)
#pragma unroll
      for (int mi = 0; mi < 2; mi++)
#pragma unroll
        for (int kk = 0; kk < 2; kk++) {
          const int row = MH * 64 + mq + mi * 16 + fr;
          af[MH][mi][kk] = *(const u16x8*)(Ab + row * 64 + (((kk * 4 + hi) ^ rb7) << 3));
        }
#pragma unroll
    for (int NH = 0; NH < 2; NH++)
#pragma unroll
      for (int ni = 0; ni < NI; ni++)
#pragma unroll
        for (int kk = 0; kk < 2; kk++) {
          const int row = NH * (BN / 2) + nq + ni * 16 + fr;
          bf[NH][ni][kk] = *(const u16x8*)(Bb + row * 64 + (((kk * 4 + hi) ^ rb7) << 3));
        }

    __builtin_amdgcn_s_setprio(1);
#pragma unroll
    for (int kk = 0; kk < 2; kk++)
#pragma unroll
      for (int MH = 0; MH < 2; MH++)
#pragma unroll
        for (int mi = 0; mi < 2; mi++)
#pragma unroll
          for (int NH = 0; NH < 2; NH++)
#pragma unroll
            for (int ni = 0; ni < NI; ni++)
              acc[MH][mi][NH][ni] = mfma16(af[MH][mi][kk], bf[NH][ni][kk], acc[MH][mi][NH][ni]);
    __builtin_amdgcn_s_setprio(0);

    s = (s + 1 >= 3) ? 0 : s + 1;
  }
#undef STG

#pragma unroll
  for (int MH = 0; MH < 2; MH++)
#pragma unroll
    for (int mi = 0; mi < 2; mi++)
#pragma unroll
      for (int NH = 0; NH < 2; NH++)
#pragma unroll
        for (int ni = 0; ni < NI; ni++)
#pragma unroll
          for (int j = 0; j < 4; j++) {
            const size_t row = m0 + MH * 64 + mq + mi * 16 + frow + j;
            const size_t col = n0 + NH * (BN / 2) + nq + ni * 16 + fr;
            if (F32OUT) ((float*)Cout)[row * Nt + col] = acc[MH][mi][NH][ni][j];
            else ((u16*)Cout)[row * Nt + col] = f2bf(acc[MH][mi][NH][ni][j]);
          }
}

// ---------------- k_normKV: kv part of qgkv -> kn, vnT (q/g handled in attn) ----------------
__global__ __launch_bounds__(256, 4) void k_normKV(const u16* __restrict__ qgkv,
                                                   u16* __restrict__ kn,
                                                   u16* __restrict__ vnT) {
  __shared__ u16 vt[128 * 64];  // [d][nl], col swizzle: c' = nl ^ ((d&15)<<2)
  const int tid = threadIdx.x, lane = tid & 63, wid = tid >> 6;
  const int hb = blockIdx.y;            // b*16 + h
  const int h = hb & 15, b = hb >> 4;
  const int n0 = blockIdx.x * 64;

  for (int s = 0; s < 16; s++) {
    const int nl = wid * 16 + s;        // 0..63
    const int n = n0 + nl;
    const size_t bn = (size_t)b * 2048 + n;
    const size_t basek = bn * 6144 + 3072 + (size_t)h * 192;

    float k = bf2f(qgkv[basek + lane]);
    float v0 = bf2f(qgkv[basek + 64 + lane]);
    float v1 = bf2f(qgkv[basek + 128 + lane]);

    float ks = k * k, vs = v0 * v0 + v1 * v1;
#pragma unroll
    for (int m = 1; m < 64; m <<= 1) {
      ks += __shfl_xor(ks, m);
      vs += __shfl_xor(vs, m);
    }
    float rk = 1.f / fmaxf(sqrtf(ks), 1e-12f);
    float rv = 1.f / fmaxf(sqrtf(vs), 1e-12f);

    kn[((size_t)hb * 2048 + n) * 64 + lane] = f2bf(k * rk);

    const int d0 = lane, d1 = 64 + lane;
    vt[d0 * 64 + (nl ^ ((d0 & 15) << 2))] = f2bf(v0 * rv);
    vt[d1 * 64 + (nl ^ ((d1 & 15) << 2))] = f2bf(v1 * rv);
  }
  __syncthreads();

  // write-out: sigma(col) = swap bits 2<->3 within n&31 (preserves bits 0-1)
#pragma unroll
  for (int p = 0; p < 8; p++) {
    const int d = p * 16 + (tid >> 4);
    const int nq = (tid & 15) * 4;
    const int cb = nq ^ ((d & 15) << 2);
    const int nq2 = (nq & ~12) | ((nq & 4) << 1) | ((nq & 8) >> 1);
    ushort4 o;
    o.x = vt[d * 64 + cb + 0];
    o.y = vt[d * 64 + cb + 1];
    o.z = vt[d * 64 + cb + 2];
    o.w = vt[d * 64 + cb + 3];
    *(ushort4*)(vnT + ((size_t)hb * 128 + d) * 2048 + n0 + nq2) = o;
  }
}

// ---------------- fused screened attention (q-norm + gate fused in) ----------------
__global__ __launch_bounds__(256, 2) void k_attn(const u16* __restrict__ qgkv,
                                                 const u16* __restrict__ kn,
                                                 const u16* __restrict__ vnT,
                                                 const float* __restrict__ ls_iaw,
                                                 const float* __restrict__ ls_hws,
                                                 u16* __restrict__ pre_out) {
  extern __shared__ char smem[];
  u16* KsB = (u16*)smem;                 // [3][64 k][64 dk]   slot stride 4096 u16
  u16* VsB = (u16*)(smem + 24576);       // [3][128 d][64 k']  slot stride 8192 u16
  u16* Os = (u16*)smem;                  // epilogue reuse: [128 q][132 d] 33.8KB

  const int tid = threadIdx.x, lane = tid & 63, wid = tid >> 6;
  const int bid = blockIdx.y * 16 + blockIdx.x;
  const int bh = (bid & 7) * 4 + ((bid >> 3) & 3);
  const int n0 = (bid >> 5) * 128;
  const int h = bh & 15, b = bh >> 4;
  const int l31 = lane & 31, L = lane >> 5, rb = l31 & 7;
  const float r = 1.f / (__expf(ls_iaw[h]) + 1.f);
  const float c1 = 1.f - r;
  const float whs = __expf(ls_hws[h]);

  // Q: load raw from qgkv, normalize in-register
  const int wq = wid * 32;
  const u16* qraw = qgkv + ((size_t)b * 2048 + n0 + wq + l31) * 6144 + (size_t)h * 192;
  u16x8 qf[4];
  float ssq = 0.f;
#pragma unroll
  for (int c = 0; c < 4; c++) {
    qf[c] = *(const u16x8*)(qraw + c * 16 + L * 8);
#pragma unroll
    for (int e = 0; e < 8; e++) { float x = bf2f(qf[c][e]); ssq += x * x; }
  }
  ssq += __shfl_xor(ssq, 32);
  const float rq = 1.f / fmaxf(sqrtf(ssq), 1e-12f);
#pragma unroll
  for (int c = 0; c < 4; c++) {
    u16x8 t;
#pragma unroll
    for (int e = 0; e < 8; e++) t[e] = f2bf(bf2f(qf[c][e]) * rq);
    qf[c] = t;
  }

  f32x16 acc[4] = {};  // acc[dt]: D[d = dt*32 + (reg&3)+8*(reg>>2)+4L][q = l31]
  const u16* kbase = kn + (size_t)bh * 2048 * 64;
  const u16* vbase = vnT + (size_t)bh * 128 * 2048;

  int ks_goff[2];
#pragma unroll
  for (int i = 0; i < 2; i++) {
    int row = wid * 16 + i * 8 + (lane >> 3);
    ks_goff[i] = row * 64 + (((lane & 7) ^ (row & 7)) << 3);
  }
  int vs_goff[4];
#pragma unroll
  for (int i = 0; i < 4; i++) {
    int row = wid * 32 + i * 8 + (lane >> 3);
    vs_goff[i] = row * 2048 + (((lane & 7) ^ (row & 7)) << 3);
  }

  // prologue: stage tile 0 -> slot 0, tile 1 -> slot 1
  {
    u16* KsC0 = KsB + wid * 1024;
    u16* VsC0 = VsB + wid * 2048;
#pragma unroll
    for (int i = 0; i < 2; i++) gload_lds16(kbase + ks_goff[i], KsC0 + i * 512);
#pragma unroll
    for (int i = 0; i < 4; i++) gload_lds16(vbase + vs_goff[i], VsC0 + i * 512);
    u16* KsC1 = KsB + 4096 + wid * 1024;
    u16* VsC1 = VsB + 8192 + wid * 2048;
#pragma unroll
    for (int i = 0; i < 2; i++) gload_lds16(kbase + (size_t)64 * 64 + ks_goff[i], KsC1 + i * 512);
#pragma unroll
    for (int i = 0; i < 4; i++) gload_lds16(vbase + (size_t)vs_goff[i] + 64, VsC1 + i * 512);
  }

  int s = 0;
  for (int t = 0; t < 32; t++) {
    if (t < 31) {
      asm volatile("s_waitcnt vmcnt(6) lgkmcnt(0)" ::: "memory");
    } else {
      asm volatile("s_waitcnt vmcnt(0) lgkmcnt(0)" ::: "memory");
    }
    __builtin_amdgcn_s_barrier();
    asm volatile("" ::: "memory");

    if (t + 2 < 32) {
      const int s2 = (s + 2 >= 3) ? s - 1 : s + 2;
      const int kv0 = (t + 2) * 64;
      u16* KsC2 = KsB + s2 * 4096 + wid * 1024;
      u16* VsC2 = VsB + s2 * 8192 + wid * 2048;
#pragma unroll
      for (int i = 0; i < 2; i++) gload_lds16(kbase + (size_t)kv0 * 64 + ks_goff[i], KsC2 + i * 512);
#pragma unroll
      for (int i = 0; i < 4; i++) gload_lds16(vbase + (size_t)vs_goff[i] + kv0, VsC2 + i * 512);
    }

    const u16* KsC = KsB + s * 4096;
    const u16* VsC = VsB + s * 8192;

    f32x16 sT0 = {}, sT1 = {};
    __builtin_amdgcn_s_setprio(1);
#pragma unroll
    for (int c = 0; c < 4; c++) {
      u16x8 kf0 = *(const u16x8*)(KsC + (0 + l31) * 64 + (((2 * c + L) ^ rb) << 3));
      u16x8 kf1 = *(const u16x8*)(KsC + (32 + l31) * 64 + (((2 * c + L) ^ rb) << 3));
      sT0 = mfma32(kf0, qf[c], sT0);
      sT1 = mfma32(kf1, qf[c], sT1);
    }
    __builtin_amdgcn_s_setprio(0);

    // screen + pack via hardware v_cvt_pk_bf16_f32 (2 f32 -> 1 u32/instr)
    uint32_t w[2][4][2];
#pragma unroll
    for (int m = 0; m < 4; m++)
#pragma unroll
      for (int p = 0; p < 2; p++) {
        float a0 = fmaxf(0.f, fmaf(r, sT0[4 * m + 2 * p], c1));
        float a1 = fmaxf(0.f, fmaf(r, sT0[4 * m + 2 * p + 1], c1));
        float b0 = fmaxf(0.f, fmaf(r, sT1[4 * m + 2 * p], c1));
        float b1 = fmaxf(0.f, fmaf(r, sT1[4 * m + 2 * p + 1], c1));
        w[0][m][p] = cvt_pk_bf16(a0 * a0, a1 * a1);
        w[1][m][p] = cvt_pk_bf16(b0 * b0, b1 * b1);
      }

    __builtin_amdgcn_s_setprio(1);
#pragma unroll
    for (int kt = 0; kt < 2; kt++)
#pragma unroll
      for (int pair = 0; pair < 2; pair++) {
        i32x4 pw;
        pw[0] = (int)w[kt][2 * pair][0];
        pw[1] = (int)w[kt][2 * pair][1];
        pw[2] = (int)w[kt][2 * pair + 1][0];
        pw[3] = (int)w[kt][2 * pair + 1][1];
        u16x8 pf = __builtin_bit_cast(u16x8, pw);
        const int chunk = 4 * kt + 2 * pair + L;
#pragma unroll
        for (int dt = 0; dt < 4; dt++) {
          u16x8 vf = *(const u16x8*)(VsC + (dt * 32 + l31) * 64 + ((chunk ^ rb) << 3));
          acc[dt] = mfma32(vf, pf, acc[dt]);
        }
      }
    __builtin_amdgcn_s_setprio(0);
    s = (s + 1 >= 3) ? 0 : s + 1;
  }

  float ss = 0.f;
#pragma unroll
  for (int dt = 0; dt < 4; dt++)
#pragma unroll
    for (int e = 0; e < 16; e++) { float x = acc[dt][e]; ss += x * x; }
  ss += __shfl_xor(ss, 32);
  float nn = sqrtf(ss);
  float scale = tanhf(nn) / fmaxf(nn, 1e-12f) * whs;

  __syncthreads();

  // epilogue: raw g from qgkv -> tanh(silu(g)) on the fly
  const int q = wq + l31;
  const size_t grow = ((size_t)b * 2048 + n0 + q) * 6144 + (size_t)h * 192 + 64;
#pragma unroll
  for (int dt = 0; dt < 4; dt++)
#pragma unroll
    for (int m = 0; m < 4; m++) {
      const int d = dt * 32 + 8 * m + 4 * L;
      ushort4 gv = *(const ushort4*)(qgkv + grow + d);
      float g0 = bf2f(gv.x), g1 = bf2f(gv.y), g2 = bf2f(gv.z), g3 = bf2f(gv.w);
      float t0 = tanhf(g0 / (1.f + __expf(-g0)));
      float t1 = tanhf(g1 / (1.f + __expf(-g1)));
      float t2 = tanhf(g2 / (1.f + __expf(-g2)));
      float t3 = tanhf(g3 / (1.f + __expf(-g3)));
      ushort4 o;
      o.x = f2bf(acc[dt][4 * m + 0] * scale * t0);
      o.y = f2bf(acc[dt][4 * m + 1] * scale * t1);
      o.z = f2bf(acc[dt][4 * m + 2] * scale * t2);
      o.w = f2bf(acc[dt][4 * m + 3] * scale * t3);
      *(ushort4*)(Os + q * 132 + d) = o;
    }
  __syncthreads();

  const int orow = tid >> 1, oc0 = (tid & 1) * 64;
  const size_t obase = ((size_t)b * 2048 + n0 + orow) * 2048 + (size_t)h * 128 + oc0;
#pragma unroll
  for (int j = 0; j < 16; j++) {
    ushort4 v = *(const ushort4*)(Os + orow * 132 + oc0 + 4 * j);
    *(ushort4*)(pre_out + obase + 4 * j) = v;
  }
}

extern "C" void kernel_launch(void* const* d_in, const int* in_sizes, int n_in,
                              void* d_out, int out_size, void* d_ws, size_t ws_size,
                              hipStream_t stream) {
  (void)in_sizes; (void)n_in; (void)out_size; (void)ws_size;
  const float* tokens = (const float*)d_in[0];
  const float* Wqg = (const float*)d_in[1];
  const float* Wkv = (const float*)d_in[2];
  const float* Wo = (const float*)d_in[3];
  const float* ls_iaw = (const float*)d_in[4];
  const float* ls_hws = (const float*)d_in[5];
  float* out = (float*)d_out;
  char* ws = (char*)d_ws;

  // workspace layout (phased aliasing):
  u16* WoT = (u16*)(ws + 0);
  char* regA = ws + 8388608;
  u16* tok_bf = (u16*)(regA);
  u16* WqgkvT = (u16*)(regA + 16777216);
  u16* kn = (u16*)(regA);
  u16* vnT = (u16*)(regA + 8388608);
  u16* pre_out = (u16*)(regA + 25165824);
  char* regB = ws + 58720256;
  u16* qgkv_raw = (u16*)(regB);

  k_cvt<<<4096, 256, 0, stream>>>(tokens, tok_bf, 8388608);
  k_cvtT<<<dim3(96, 64), 256, 0, stream>>>(Wqg, WqgkvT, 2048, 3072);
  k_cvtT<<<dim3(96, 64), 256, 0, stream>>>(Wkv, WqgkvT + (size_t)3072 * 2048, 2048, 3072);
  k_cvtT<<<dim3(64, 64), 256, 0, stream>>>(Wo, WoT, 2048, 2048);

  // merged projection: 256x384 tile, grid 256 = 1 exact round, 120KB LDS triple-buffer
  k_gemmP2<<<256, 512, 122880, stream>>>(tok_bf, WqgkvT, qgkv_raw, 6144, 2048);

  // k/v normalize only (q-norm and gate fused into attn)
  k_normKV<<<dim3(32, 32), 256, 0, stream>>>(qgkv_raw, kn, vnT);

  // attn: 72KB LDS (3-slot K/V), 2 blocks/CU; reads qgkv_raw (q,g) + kn + vnT
  k_attn<<<dim3(16, 32), 256, 73728, stream>>>(qgkv_raw, kn, vnT, ls_iaw, ls_hws, pre_out);

  // final projection: 128x256 tile, grid 256 = 1 exact round, 144KB LDS triple-buffer
  k_gemmU<2, 1><<<256, 512, 147456, stream>>>(pre_out, WoT, out, 2048, 2048);
}